// Round 11
// baseline (333.815 us; speedup 1.0000x reference)
//
#include <hip/hip_runtime.h>
#include <stdint.h>

// ---------- types & helpers ----------
typedef short bf16x8 __attribute__((ext_vector_type(8)));
typedef float f32x4 __attribute__((ext_vector_type(4)));

__device__ __forceinline__ uint16_t f2b(float f) {
    uint32_t u = __builtin_bit_cast(uint32_t, f);
    return (uint16_t)((u + 0x7fffu + ((u >> 16) & 1u)) >> 16);
}

__device__ __forceinline__ void gll16(const void* g, void* l) {
    __builtin_amdgcn_global_load_lds(
        (const __attribute__((address_space(1))) uint32_t*)(uintptr_t)g,
        (__attribute__((address_space(3))) uint32_t*)(uint32_t)(uintptr_t)l,
        16, 0, 0);
}

// ---------- bijective XCD-chunked block swizzle (requires nblocks % 8 == 0) ----
__device__ __forceinline__ void swz3(int& bx, int& by, int& bz) {
    const int nx = gridDim.x, ny = gridDim.y, nz = gridDim.z;
    const int n = nx * ny * nz;
    int orig = blockIdx.x + nx * (blockIdx.y + ny * blockIdx.z);
    int l = (orig & 7) * (n >> 3) + (orig >> 3);
    bx = l % nx; l /= nx;
    by = l % ny;
    bz = l / ny;
}

// ---------- prep: {x -> xb + xT} and {W -> W^T bf16}, 16B/lane everywhere ----
// LDS: flat 64x64 u16 tile, 16B-block XOR swizzle keyed (row>>3)&7.
//   store:  tile[row*64 + ((c8>>3)^((row>>3)&7))*8]          (uint4, aligned)
//   read:   tile[tok*64 + (((a>>3)^((tok>>3)&7))*8 + (a&7)]  (u16 scalar, 2-way)
struct Ptr4 { const float* p[4]; };

__global__ __launch_bounds__(256) void prep(const float* __restrict__ x,
                                            uint16_t* __restrict__ xb,
                                            uint16_t* __restrict__ xT,
                                            Ptr4 wp, uint16_t* __restrict__ Wt) {
    __shared__ uint16_t tile[4096];   // 8 KB
    const int t = threadIdx.x;
    const int c8 = (t & 7) * 8;
    int id = blockIdx.x;
    if (id < 4096) {
        const int d0 = (id & 15) * 64;         // feature tile
        const int n0 = ((id >> 4) & 63) * 64;  // token tile
        const int b = id >> 10;
        const float* xbase = x + (size_t)b * 4194304;
#pragma unroll
        for (int p = 0; p < 2; p++) {
            int row = p * 32 + (t >> 3);       // token-local
            const float* s = &xbase[(size_t)(n0 + row) * 1024 + d0 + c8];
            float4 v0 = *(const float4*)s;
            float4 v1 = *(const float4*)(s + 4);
            uint4 pk;
            pk.x = (uint32_t)f2b(v0.x) | ((uint32_t)f2b(v0.y) << 16);
            pk.y = (uint32_t)f2b(v0.z) | ((uint32_t)f2b(v0.w) << 16);
            pk.z = (uint32_t)f2b(v1.x) | ((uint32_t)f2b(v1.y) << 16);
            pk.w = (uint32_t)f2b(v1.z) | ((uint32_t)f2b(v1.w) << 16);
            *(uint4*)&xb[(size_t)(b * 4096 + n0 + row) * 1024 + d0 + c8] = pk;
            int blk = (c8 >> 3) ^ ((row >> 3) & 7);
            *(uint4*)&tile[row * 64 + blk * 8] = pk;
        }
        __syncthreads();
        uint16_t* oT = xT + (size_t)b * 4194304;
#pragma unroll
        for (int p = 0; p < 2; p++) {
            int a = p * 32 + (t >> 3);         // feature-local
            int tok8 = c8;                     // token-local, 8 consecutive
            uint16_t vv[8];
#pragma unroll
            for (int k = 0; k < 8; k++) {
                int tok = tok8 + k;
                int blk = (a >> 3) ^ ((tok >> 3) & 7);
                vv[k] = tile[tok * 64 + blk * 8 + (a & 7)];
            }
            uint4 pk;
            pk.x = (uint32_t)vv[0] | ((uint32_t)vv[1] << 16);
            pk.y = (uint32_t)vv[2] | ((uint32_t)vv[3] << 16);
            pk.z = (uint32_t)vv[4] | ((uint32_t)vv[5] << 16);
            pk.w = (uint32_t)vv[6] | ((uint32_t)vv[7] << 16);
            *(uint4*)&oT[(size_t)(d0 + a) * 4096 + n0 + tok8] = pk;
        }
    } else {
        id -= 4096;
        const int c0 = (id & 15) * 64;         // e tile (cols of W)
        const int r0 = ((id >> 4) & 15) * 64;  // d tile (rows of W)
        const int m = id >> 8;
        const float* in = wp.p[m];
        uint16_t* o = Wt + (size_t)m * 1048576;
#pragma unroll
        for (int p = 0; p < 2; p++) {
            int row = p * 32 + (t >> 3);       // d-local
            const float* s = &in[(size_t)(r0 + row) * 1024 + c0 + c8];
            float4 v0 = *(const float4*)s;
            float4 v1 = *(const float4*)(s + 4);
            uint4 pk;
            pk.x = (uint32_t)f2b(v0.x) | ((uint32_t)f2b(v0.y) << 16);
            pk.y = (uint32_t)f2b(v0.z) | ((uint32_t)f2b(v0.w) << 16);
            pk.z = (uint32_t)f2b(v1.x) | ((uint32_t)f2b(v1.y) << 16);
            pk.w = (uint32_t)f2b(v1.z) | ((uint32_t)f2b(v1.w) << 16);
            int blk = (c8 >> 3) ^ ((row >> 3) & 7);
            *(uint4*)&tile[row * 64 + blk * 8] = pk;
        }
        __syncthreads();
#pragma unroll
        for (int p = 0; p < 2; p++) {
            int a = p * 32 + (t >> 3);         // e-local
            int tok8 = c8;                     // d-local, 8 consecutive
            uint16_t vv[8];
#pragma unroll
            for (int k = 0; k < 8; k++) {
                int dd = tok8 + k;
                int blk = (a >> 3) ^ ((dd >> 3) & 7);
                vv[k] = tile[dd * 64 + blk * 8 + (a & 7)];
            }
            uint4 pk;
            pk.x = (uint32_t)vv[0] | ((uint32_t)vv[1] << 16);
            pk.y = (uint32_t)vv[2] | ((uint32_t)vv[3] << 16);
            pk.z = (uint32_t)vv[4] | ((uint32_t)vv[5] << 16);
            pk.w = (uint32_t)vv[6] | ((uint32_t)vv[7] << 16);
            *(uint4*)&o[(size_t)(c0 + a) * 1024 + r0 + tok8] = pk;
        }
    }
}

// ---------- qbuf dual-B gated projection (verified; mbase = token offset) ----
__global__ __launch_bounds__(512, 2) void proj_gate8(const uint16_t* __restrict__ A,
                                                     const uint16_t* __restrict__ Wt,
                                                     uint16_t* __restrict__ Q,
                                                     int mbase) {
    __shared__ uint16_t lds[65536];   // 128 KB = 4 qbufs x 16384 u16
    const int t = threadIdx.x;
    const int wave = t >> 6;
    const int lane = t & 63;
    int bx, by, bz;
    swz3(bx, by, bz);
    const int m0 = mbase + by * 256;
    const int e0 = bx * 128;
    const uint16_t* B1 = Wt + (size_t)e0 * 1024;
    const uint16_t* B2 = Wt + 1048576 + (size_t)e0 * 1024;
    const int wm = (wave >> 1) * 64;
    const int wn = (wave & 1) * 64;

    int LsA0 = t * 16;
    int LsA1 = 8192 + t * 16;
    int gbA0 = LsA0 ^ (((LsA0 >> 7) & 7) << 4);
    int gbA1 = LsA1 ^ (((LsA1 >> 7) & 7) << 4);
    int gbB  = gbA0;
    const uint16_t* srcA0 = A + (size_t)(m0 + (gbA0 >> 6)) * 1024 + ((gbA0 & 63) >> 1);
    const uint16_t* srcA1 = A + (size_t)(m0 + (gbA1 >> 6)) * 1024 + ((gbA1 & 63) >> 1);
    const uint16_t* srcB1 = B1 + (size_t)(gbB >> 6) * 1024 + ((gbB & 63) >> 1);
    const uint16_t* srcB2 = B2 + (size_t)(gbB >> 6) * 1024 + ((gbB & 63) >> 1);

    auto STAGE = [&](int kt_, int ks_) {
        const int h = (2 * kt_ + ks_) & 3;
        const int kb = kt_ * 64 + ks_ * 32;
        uint16_t* db = lds + h * 16384 + (wave << 9);
        gll16(srcA0 + kb, db);
        gll16(srcA1 + kb, db + 4096);
        gll16(srcB1 + kb, db + 8192);
        gll16(srcB2 + kb, db + 12288);
    };

    const int cb = (lane >> 4) << 4;
    int aoff[4], b1off[4], b2off[4];
#pragma unroll
    for (int i = 0; i < 4; i++) {
        int g = (wm + i * 16 + (lane & 15)) * 64 + cb;
        aoff[i] = (g ^ (((g >> 7) & 7) << 4)) >> 1;
    }
#pragma unroll
    for (int j = 0; j < 4; j++) {
        int g = (wn + j * 16 + (lane & 15)) * 64 + cb;
        int sw = (g ^ (((g >> 7) & 7) << 4)) >> 1;
        b1off[j] = 8192 + sw;
        b2off[j] = 12288 + sw;
    }

    f32x4 acc1[4][4] = {};
    f32x4 acc2[4][4] = {};

    STAGE(0, 0); STAGE(0, 1); STAGE(1, 0); STAGE(1, 1);
    asm volatile("s_waitcnt vmcnt(12)" ::: "memory");
    __builtin_amdgcn_s_barrier();

    for (int kt = 0; kt < 16; ++kt) {
        const uint16_t* lb0 = lds + ((2 * kt) & 3) * 16384;
        const uint16_t* lb1 = lds + ((2 * kt + 1) & 3) * 16384;
        bf16x8 af[4], bq[4];

        // phase 1: A(ks0)+B1(ks0) -> acc1
#pragma unroll
        for (int i = 0; i < 4; i++) af[i] = *(const bf16x8*)&lb0[aoff[i]];
#pragma unroll
        for (int j = 0; j < 4; j++) bq[j] = *(const bf16x8*)&lb0[b1off[j]];
        __builtin_amdgcn_s_barrier();
        asm volatile("s_waitcnt lgkmcnt(0)" ::: "memory");
        __builtin_amdgcn_sched_barrier(0);
        __builtin_amdgcn_s_setprio(1);
#pragma unroll
        for (int i = 0; i < 4; i++)
#pragma unroll
            for (int j = 0; j < 4; j++)
                acc1[i][j] = __builtin_amdgcn_mfma_f32_16x16x32_bf16(af[i], bq[j],
                                                                     acc1[i][j], 0, 0, 0);
        __builtin_amdgcn_s_setprio(0);
        __builtin_amdgcn_s_barrier();

        // phase 2: B2(ks0) -> acc2
#pragma unroll
        for (int j = 0; j < 4; j++) bq[j] = *(const bf16x8*)&lb0[b2off[j]];
        __builtin_amdgcn_s_barrier();
        asm volatile("s_waitcnt lgkmcnt(0)" ::: "memory");
        __builtin_amdgcn_sched_barrier(0);
        __builtin_amdgcn_s_setprio(1);
#pragma unroll
        for (int i = 0; i < 4; i++)
#pragma unroll
            for (int j = 0; j < 4; j++)
                acc2[i][j] = __builtin_amdgcn_mfma_f32_16x16x32_bf16(af[i], bq[j],
                                                                     acc2[i][j], 0, 0, 0);
        __builtin_amdgcn_s_setprio(0);
        if (kt < 15) { asm volatile("s_waitcnt vmcnt(8)" ::: "memory"); }
        else         { asm volatile("s_waitcnt vmcnt(0)" ::: "memory"); }
        __builtin_amdgcn_s_barrier();
        if (kt < 14) STAGE(kt + 2, 0);

        // phase 3: A(ks1)+B1(ks1) -> acc1
#pragma unroll
        for (int i = 0; i < 4; i++) af[i] = *(const bf16x8*)&lb1[aoff[i]];
#pragma unroll
        for (int j = 0; j < 4; j++) bq[j] = *(const bf16x8*)&lb1[b1off[j]];
        __builtin_amdgcn_s_barrier();
        asm volatile("s_waitcnt lgkmcnt(0)" ::: "memory");
        __builtin_amdgcn_sched_barrier(0);
        __builtin_amdgcn_s_setprio(1);
#pragma unroll
        for (int i = 0; i < 4; i++)
#pragma unroll
            for (int j = 0; j < 4; j++)
                acc1[i][j] = __builtin_amdgcn_mfma_f32_16x16x32_bf16(af[i], bq[j],
                                                                     acc1[i][j], 0, 0, 0);
        __builtin_amdgcn_s_setprio(0);
        __builtin_amdgcn_s_barrier();

        // phase 4: B2(ks1) -> acc2
#pragma unroll
        for (int j = 0; j < 4; j++) bq[j] = *(const bf16x8*)&lb1[b2off[j]];
        __builtin_amdgcn_s_barrier();
        asm volatile("s_waitcnt lgkmcnt(0)" ::: "memory");
        __builtin_amdgcn_sched_barrier(0);
        __builtin_amdgcn_s_setprio(1);
#pragma unroll
        for (int i = 0; i < 4; i++)
#pragma unroll
            for (int j = 0; j < 4; j++)
                acc2[i][j] = __builtin_amdgcn_mfma_f32_16x16x32_bf16(af[i], bq[j],
                                                                     acc2[i][j], 0, 0, 0);
        __builtin_amdgcn_s_setprio(0);
        if (kt < 14)       { asm volatile("s_waitcnt vmcnt(8)" ::: "memory"); }
        else if (kt == 14) { asm volatile("s_waitcnt vmcnt(4)" ::: "memory"); }
        else               { asm volatile("s_waitcnt vmcnt(0)" ::: "memory"); }
        __builtin_amdgcn_s_barrier();
        if (kt < 14) STAGE(kt + 2, 1);
    }

    const int rl = (lane >> 4) * 4;
    const int cl = lane & 15;
#pragma unroll
    for (int i = 0; i < 4; i++)
#pragma unroll
        for (int j = 0; j < 4; j++)
#pragma unroll
            for (int r = 0; r < 4; r++) {
                float g = acc1[i][j][r] * acc2[i][j][r];
                Q[(size_t)(m0 + wm + i * 16 + rl + r) * 1024 + e0 + wn + j * 16 + cl] = f2b(g);
            }
}

// ---------- qbuf Gram GEMM: P[z=(batch,ks)] = xT-slice @ xT-slice^T ----------
__global__ __launch_bounds__(512, 2) void gram8(const uint16_t* __restrict__ xT,
                                                float* __restrict__ P) {
    __shared__ uint16_t lds[49152];   // 96 KB = 4 qbufs x 12288 u16
    const int t = threadIdx.x;
    const int wave = t >> 6;
    const int lane = t & 63;
    int bx, by, bz;
    swz3(bx, by, bz);
    const int m0 = by * 256;
    const int n0 = bx * 128;
    const int batch = bz >> 1, ks = bz & 1;
    const uint16_t* Xb = xT + (size_t)batch * 4194304 + ks * 2048;
    const int wm = (wave >> 1) * 64;
    const int wn = (wave & 1) * 64;

    int LsA0 = t * 16;
    int LsA1 = 8192 + t * 16;
    int gbA0 = LsA0 ^ (((LsA0 >> 7) & 7) << 4);
    int gbA1 = LsA1 ^ (((LsA1 >> 7) & 7) << 4);
    int gbB  = gbA0;
    const uint16_t* srcA0 = Xb + (size_t)(m0 + (gbA0 >> 6)) * 4096 + ((gbA0 & 63) >> 1);
    const uint16_t* srcA1 = Xb + (size_t)(m0 + (gbA1 >> 6)) * 4096 + ((gbA1 & 63) >> 1);
    const uint16_t* srcB  = Xb + (size_t)(n0 + (gbB  >> 6)) * 4096 + ((gbB  & 63) >> 1);

    auto STAGE = [&](int kt_, int ks2_) {
        const int h = (2 * kt_ + ks2_) & 3;
        const int kb = kt_ * 64 + ks2_ * 32;
        uint16_t* db = lds + h * 12288 + (wave << 9);
        gll16(srcA0 + kb, db);            // A rows   0..127
        gll16(srcA1 + kb, db + 4096);     // A rows 128..255
        gll16(srcB  + kb, db + 8192);     // B rows   0..127
    };

    const int cb = (lane >> 4) << 4;
    int aoff[4], boff[4];
#pragma unroll
    for (int i = 0; i < 4; i++) {
        int g = (wm + i * 16 + (lane & 15)) * 64 + cb;
        aoff[i] = (g ^ (((g >> 7) & 7) << 4)) >> 1;
    }
#pragma unroll
    for (int j = 0; j < 4; j++) {
        int g = (wn + j * 16 + (lane & 15)) * 64 + cb;
        boff[j] = 8192 + ((g ^ (((g >> 7) & 7) << 4)) >> 1);
    }

    f32x4 acc[4][4] = {};

    STAGE(0, 0); STAGE(0, 1); STAGE(1, 0); STAGE(1, 1);
    asm volatile("s_waitcnt vmcnt(9)" ::: "memory");
    __builtin_amdgcn_s_barrier();

    for (int kt = 0; kt < 32; ++kt) {
        const uint16_t* lb0 = lds + ((2 * kt) & 3) * 12288;
        const uint16_t* lb1 = lds + ((2 * kt + 1) & 3) * 12288;
        bf16x8 af[4], bq[4];

        // phase ks2=0
#pragma unroll
        for (int i = 0; i < 4; i++) af[i] = *(const bf16x8*)&lb0[aoff[i]];
#pragma unroll
        for (int j = 0; j < 4; j++) bq[j] = *(const bf16x8*)&lb0[boff[j]];
        __builtin_amdgcn_s_barrier();
        asm volatile("s_waitcnt lgkmcnt(0)" ::: "memory");
        __builtin_amdgcn_sched_barrier(0);
        __builtin_amdgcn_s_setprio(1);
#pragma unroll
        for (int i = 0; i < 4; i++)
#pragma unroll
            for (int j = 0; j < 4; j++)
                acc[i][j] = __builtin_amdgcn_mfma_f32_16x16x32_bf16(af[i], bq[j],
                                                                    acc[i][j], 0, 0, 0);
        __builtin_amdgcn_s_setprio(0);
        if (kt < 31) { asm volatile("s_waitcnt vmcnt(6)" ::: "memory"); }
        else         { asm volatile("s_waitcnt vmcnt(0)" ::: "memory"); }
        __builtin_amdgcn_s_barrier();
        if (kt < 30) STAGE(kt + 2, 0);

        // phase ks2=1
#pragma unroll
        for (int i = 0; i < 4; i++) af[i] = *(const bf16x8*)&lb1[aoff[i]];
#pragma unroll
        for (int j = 0; j < 4; j++) bq[j] = *(const bf16x8*)&lb1[boff[j]];
        __builtin_amdgcn_s_barrier();
        asm volatile("s_waitcnt lgkmcnt(0)" ::: "memory");
        __builtin_amdgcn_sched_barrier(0);
        __builtin_amdgcn_s_setprio(1);
#pragma unroll
        for (int i = 0; i < 4; i++)
#pragma unroll
            for (int j = 0; j < 4; j++)
                acc[i][j] = __builtin_amdgcn_mfma_f32_16x16x32_bf16(af[i], bq[j],
                                                                    acc[i][j], 0, 0, 0);
        __builtin_amdgcn_s_setprio(0);
        if (kt < 30)       { asm volatile("s_waitcnt vmcnt(6)" ::: "memory"); }
        else if (kt == 30) { asm volatile("s_waitcnt vmcnt(3)" ::: "memory"); }
        else               { asm volatile("s_waitcnt vmcnt(0)" ::: "memory"); }
        __builtin_amdgcn_s_barrier();
        if (kt < 30) STAGE(kt + 2, 1);
    }

    float* Pb = P + (size_t)bz * 1048576;
    const int crow = m0 + wm + (lane >> 4) * 4;
    const int ccol = n0 + wn + (lane & 15);
#pragma unroll
    for (int i = 0; i < 4; i++)
#pragma unroll
        for (int j = 0; j < 4; j++)
#pragma unroll
            for (int r = 0; r < 4; r++)
                Pb[(size_t)(crow + i * 16 + r) * 1024 + ccol + j * 16] = acc[i][j][r];
}

// ---------- reduce 2 fp32 partials -> bf16 (G = x^T x per batch) ----------
__global__ __launch_bounds__(256) void reduce_kv(const float4* __restrict__ P,
                                                 uint2* __restrict__ G) {
    int i = blockIdx.x * 256 + threadIdx.x;
    int b = i >> 18;
    int r = i & 262143;
    const float4* base = P + (size_t)b * 524288 + r;
    float4 s0 = base[0];
    float4 s1 = base[262144];
    float x = s0.x + s1.x;
    float y = s0.y + s1.y;
    float zz = s0.z + s1.z;
    float w = s0.w + s1.w;
    uint2 o;
    o.x = (uint32_t)f2b(x) | ((uint32_t)f2b(y) << 16);
    o.y = (uint32_t)f2b(zz) | ((uint32_t)f2b(w) << 16);
    G[i] = o;
}

// ---------- generic 128x128-tile GEMM, K=1024, bf16 out ----------
__global__ __launch_bounds__(256) void gemm_nt_bf16(const uint16_t* __restrict__ A,
                                                    int lda, int az,
                                                    const uint16_t* __restrict__ Bt,
                                                    int ldb,
                                                    uint16_t* __restrict__ C,
                                                    int ldc, int cz) {
    int bxs, bys, bzs;
    swz3(bxs, bys, bzs);
    const uint16_t* Ab = A + (size_t)bzs * az;
    uint16_t* Cb = C + (size_t)bzs * cz;

    __shared__ uint16_t lA[4096];
    __shared__ uint16_t lB[4096];

    const int t = threadIdx.x;
    const int wave = t >> 6;
    const int lane = t & 63;
    const int m0 = bys * 128;
    const int n0 = bxs * 128;
    const int wm = (wave >> 1) * 64;
    const int wn = (wave & 1) * 64;

    const uint16_t* gA0 = Ab + (size_t)(m0 + (t >> 2)) * lda + (t & 3) * 8;
    const uint16_t* gB0 = Bt + (size_t)(n0 + (t >> 2)) * ldb + (t & 3) * 8;
    uint16_t* lA0 = lA + wave * 512;
    uint16_t* lA1 = lA + 2048 + wave * 512;
    uint16_t* lB0 = lB + wave * 512;
    uint16_t* lB1 = lB + 2048 + wave * 512;

    f32x4 acc[4][4] = {};

    const int arow = wm + (lane & 15);
    const int brow = wn + (lane & 15);
    const int koff = (lane >> 4) * 8;

    for (int k0 = 0; k0 < 1024; k0 += 32) {
        __syncthreads();
        gll16(gA0 + k0, lA0);
        gll16(gA0 + (size_t)64 * lda + k0, lA1);
        gll16(gB0 + k0, lB0);
        gll16(gB0 + (size_t)64 * ldb + k0, lB1);
        __syncthreads();

        bf16x8 af[4], bfr[4];
#pragma unroll
        for (int i = 0; i < 4; i++)
            af[i] = *(const bf16x8*)&lA[(arow + i * 16) * 32 + koff];
#pragma unroll
        for (int i = 0; i < 4; i++)
            bfr[i] = *(const bf16x8*)&lB[(brow + i * 16) * 32 + koff];
#pragma unroll
        for (int i = 0; i < 4; i++)
#pragma unroll
            for (int j = 0; j < 4; j++)
                acc[i][j] = __builtin_amdgcn_mfma_f32_16x16x32_bf16(af[i], bfr[j],
                                                                    acc[i][j], 0, 0, 0);
    }

    const int crow = m0 + wm + (lane >> 4) * 4;
    const int ccol = n0 + wn + (lane & 15);
#pragma unroll
    for (int i = 0; i < 4; i++)
#pragma unroll
        for (int j = 0; j < 4; j++)
#pragma unroll
            for (int r = 0; r < 4; r++)
                Cb[(size_t)(crow + i * 16 + r) * ldc + ccol + j * 16] = f2b(acc[i][j][r]);
}

// ---------- qbuf out GEMM: out = Q @ kvT^T, fp32 (verified) ----------
__global__ __launch_bounds__(512, 2) void gemm_out8(const uint16_t* __restrict__ A,
                                                    const uint16_t* __restrict__ kvT,
                                                    float* __restrict__ C) {
    __shared__ uint16_t lds[65536];
    const int t = threadIdx.x;
    const int wave = t >> 6;
    const int lane = t & 63;
    int bx, by, bz;
    swz3(bx, by, bz);
    const int m0 = by * 256;
    const int n0 = bx * 256;
    const int batch = by >> 4;
    const uint16_t* Bb = kvT + (size_t)batch * 1048576 + (size_t)n0 * 1024;
    const int wm = (wave >> 2) * 128;
    const int wn = (wave & 3) * 64;

    int Ls0 = t * 16;
    int Ls1 = 8192 + t * 16;
    int gb0 = Ls0 ^ (((Ls0 >> 7) & 7) << 4);
    int gb1 = Ls1 ^ (((Ls1 >> 7) & 7) << 4);
    const uint16_t* srcA0 = A + (size_t)(m0 + (gb0 >> 6)) * 1024 + ((gb0 & 63) >> 1);
    const uint16_t* srcA1 = A + (size_t)(m0 + (gb1 >> 6)) * 1024 + ((gb1 & 63) >> 1);
    const uint16_t* srcB0 = Bb + (size_t)(gb0 >> 6) * 1024 + ((gb0 & 63) >> 1);
    const uint16_t* srcB1 = Bb + (size_t)(gb1 >> 6) * 1024 + ((gb1 & 63) >> 1);

    auto STAGE = [&](int kt_, int ks_) {
        const int h = (2 * kt_ + ks_) & 3;
        const int kb = kt_ * 64 + ks_ * 32;
        uint16_t* db = lds + h * 16384 + (wave << 9);
        gll16(srcA0 + kb, db);
        gll16(srcA1 + kb, db + 4096);
        gll16(srcB0 + kb, db + 8192);
        gll16(srcB1 + kb, db + 12288);
    };

    const int cb = (lane >> 4) << 4;
    int aoff[8], boff[4];
#pragma unroll
    for (int i = 0; i < 8; i++) {
        int g = (wm + i * 16 + (lane & 15)) * 64 + cb;
        aoff[i] = (g ^ (((g >> 7) & 7) << 4)) >> 1;
    }
#pragma unroll
    for (int j = 0; j < 4; j++) {
        int g = (wn + j * 16 + (lane & 15)) * 64 + cb;
        boff[j] = 8192 + ((g ^ (((g >> 7) & 7) << 4)) >> 1);
    }

    f32x4 acc[8][4] = {};

    STAGE(0, 0); STAGE(0, 1); STAGE(1, 0); STAGE(1, 1);
    asm volatile("s_waitcnt vmcnt(12)" ::: "memory");
    __builtin_amdgcn_s_barrier();

    for (int kt = 0; kt < 16; ++kt) {
        const uint16_t* lb0 = lds + ((2 * kt) & 3) * 16384;
        const uint16_t* lb1 = lds + ((2 * kt + 1) & 3) * 16384;
        bf16x8 af[8], bq[4];

        // phase ks0
#pragma unroll
        for (int i = 0; i < 8; i++) af[i] = *(const bf16x8*)&lb0[aoff[i]];
#pragma unroll
        for (int j = 0; j < 4; j++) bq[j] = *(const bf16x8*)&lb0[boff[j]];
        __builtin_amdgcn_s_barrier();
        asm volatile("s_waitcnt lgkmcnt(0)" ::: "memory");
        __builtin_amdgcn_sched_barrier(0);
        __builtin_amdgcn_s_setprio(1);
#pragma unroll
        for (int i = 0; i < 8; i++)
#pragma unroll
            for (int j = 0; j < 4; j++)
                acc[i][j] = __builtin_amdgcn_mfma_f32_16x16x32_bf16(af[i], bq[j],
                                                                    acc[i][j], 0, 0, 0);
        __builtin_amdgcn_s_setprio(0);
        if (kt < 15) { asm volatile("s_waitcnt vmcnt(8)" ::: "memory"); }
        else         { asm volatile("s_waitcnt vmcnt(0)" ::: "memory"); }
        __builtin_amdgcn_s_barrier();
        if (kt < 14) STAGE(kt + 2, 0);

        // phase ks1
#pragma unroll
        for (int i = 0; i < 8; i++) af[i] = *(const bf16x8*)&lb1[aoff[i]];
#pragma unroll
        for (int j = 0; j < 4; j++) bq[j] = *(const bf16x8*)&lb1[boff[j]];
        __builtin_amdgcn_s_barrier();
        asm volatile("s_waitcnt lgkmcnt(0)" ::: "memory");
        __builtin_amdgcn_sched_barrier(0);
        __builtin_amdgcn_s_setprio(1);
#pragma unroll
        for (int i = 0; i < 8; i++)
#pragma unroll
            for (int j = 0; j < 4; j++)
                acc[i][j] = __builtin_amdgcn_mfma_f32_16x16x32_bf16(af[i], bq[j],
                                                                    acc[i][j], 0, 0, 0);
        __builtin_amdgcn_s_setprio(0);
        if (kt < 14)       { asm volatile("s_waitcnt vmcnt(8)" ::: "memory"); }
        else if (kt == 14) { asm volatile("s_waitcnt vmcnt(4)" ::: "memory"); }
        else               { asm volatile("s_waitcnt vmcnt(0)" ::: "memory"); }
        __builtin_amdgcn_s_barrier();
        if (kt < 14) STAGE(kt + 2, 1);
    }

    const int rl = (lane >> 4) * 4;
    const int cl = lane & 15;
#pragma unroll
    for (int i = 0; i < 8; i++)
#pragma unroll
        for (int j = 0; j < 4; j++)
#pragma unroll
            for (int r = 0; r < 4; r++)
                C[(size_t)(m0 + wm + i * 16 + rl + r) * 1024 + n0 + wn + j * 16 + cl] =
                    acc[i][j][r];
}

// ---------- launch ----------
extern "C" void kernel_launch(void* const* d_in, const int* in_sizes, int n_in,
                              void* d_out, int out_size, void* d_ws, size_t ws_size,
                              hipStream_t stream) {
    const float* x = (const float*)d_in[0];

    uint16_t* ws  = (uint16_t*)d_ws;
    uint16_t* xb  = ws;                        // [0,32MB)    x bf16 row-major
    uint16_t* xT  = ws + 16777216;             // [32,64MB)   x^T bf16 [4][1024][4096]
    uint16_t* Wt  = ws + 33554432;             // [64,72MB)   W^T x4 bf16
    uint16_t* Q   = ws + 37748736;             // [72,104MB)  gated query bf16
    float*    P   = (float*)(ws + 54525952);   // [104,136MB) fp32 Gram partials
    uint16_t* G   = ws + 71303168;             // [136,144MB) G = x^T x bf16
    uint16_t* H   = ws + 75497472;             // [144,152MB) H = Wv^T G  [1024][4096]
    uint16_t* kvT = ws + 79691776;             // [152,160MB) kv^T bf16 [4][1024][1024]

    // 1. fused prep: x -> xb+xT, weights -> W^T (16B/lane, swizzled LDS)
    Ptr4 wp;
    wp.p[0] = (const float*)d_in[1];
    wp.p[1] = (const float*)d_in[2];
    wp.p[2] = (const float*)d_in[3];
    wp.p[3] = (const float*)d_in[4];
    prep<<<5120, 256, 0, stream>>>(x, xb, xT, wp, Wt);

    // 2. gated query projection — two 256-block halves (1 block/CU each)
    proj_gate8<<<dim3(8, 32), 512, 0, stream>>>(xb, Wt, Q, 0);
    proj_gate8<<<dim3(8, 32), 512, 0, stream>>>(xb, Wt, Q, 8192);

    // 3. Gram partials: qbuf pipeline, split-K=2, 256x128 tiles (256 blocks)
    gram8<<<dim3(8, 4, 8), 512, 0, stream>>>(xT, P);

    // 4. reduce partials -> G bf16
    reduce_kv<<<4096, 256, 0, stream>>>((const float4*)P, (uint2*)G);

    // 5. H = Wv^T @ G  (G symmetric -> rows as B)
    gemm_nt_bf16<<<dim3(32, 8, 1), 256, 0, stream>>>(Wt + 3 * 1048576, 1024, 0,
                                                     G, 1024, H, 4096, 0);

    // 6. kvT[b] = H[:, b*1024:(b+1)*1024] @ Wk
    gemm_nt_bf16<<<dim3(8, 8, 4), 256, 0, stream>>>(H, 4096, 1024,
                                                    Wt + 2 * 1048576, 1024,
                                                    kvT, 1024, 1048576);

    // 7. out = Q @ kvT^T (qbuf pipeline)
    gemm_out8<<<dim3(4, 64), 512, 0, stream>>>(Q, kvT, (float*)d_out);
}

// Round 12
// 327.585 us; speedup vs baseline: 1.0190x; 1.0190x over previous
//
#include <hip/hip_runtime.h>
#include <stdint.h>

// ---------- types & helpers ----------
typedef short bf16x8 __attribute__((ext_vector_type(8)));
typedef float f32x4 __attribute__((ext_vector_type(4)));

__device__ __forceinline__ uint16_t f2b(float f) {
    uint32_t u = __builtin_bit_cast(uint32_t, f);
    return (uint16_t)((u + 0x7fffu + ((u >> 16) & 1u)) >> 16);
}

__device__ __forceinline__ uint4 pack8(float4 a, float4 b) {
    uint4 p;
    p.x = (uint32_t)f2b(a.x) | ((uint32_t)f2b(a.y) << 16);
    p.y = (uint32_t)f2b(a.z) | ((uint32_t)f2b(a.w) << 16);
    p.z = (uint32_t)f2b(b.x) | ((uint32_t)f2b(b.y) << 16);
    p.w = (uint32_t)f2b(b.z) | ((uint32_t)f2b(b.w) << 16);
    return p;
}

__device__ __forceinline__ void gll16(const void* g, void* l) {
    __builtin_amdgcn_global_load_lds(
        (const __attribute__((address_space(1))) uint32_t*)(uintptr_t)g,
        (__attribute__((address_space(3))) uint32_t*)(uint32_t)(uintptr_t)l,
        16, 0, 0);
}

// ---------- bijective XCD-chunked block swizzle (requires nblocks % 8 == 0) ----
__device__ __forceinline__ void swz3(int& bx, int& by, int& bz) {
    const int nx = gridDim.x, ny = gridDim.y, nz = gridDim.z;
    const int n = nx * ny * nz;
    int orig = blockIdx.x + nx * (blockIdx.y + ny * blockIdx.z);
    int l = (orig & 7) * (n >> 3) + (orig >> 3);
    bx = l % nx; l /= nx;
    by = l % ny;
    bz = l / ny;
}

// ---------- prep: {x -> xb + xT} and {W -> W^T bf16} ----------
// 4 tiles/block, software-pipelined: tile tau+1's global loads (to regs) are
// issued before tile tau's convert/transpose, hiding HBM latency (round-11
// diagnosis: latency-bound, occupancy 58%, HBM 41%, conflicts 0, VALU 6%).
// A block's 4 tiles share rows (n0,b const), d0 spans 4 consecutive 64-col
// strips -> 1KB-contiguous reads per row. LDS tile layout unchanged
// (16B-block XOR swizzle, conflict-free, verified r11). Bit-identical math.
struct Ptr4 { const float* p[4]; };

__global__ __launch_bounds__(256) void prep(const float* __restrict__ x,
                                            uint16_t* __restrict__ xb,
                                            uint16_t* __restrict__ xT,
                                            Ptr4 wp, uint16_t* __restrict__ Wt) {
    __shared__ uint16_t tile[4096];   // 8 KB
    const int t = threadIdx.x;
    const int c8 = (t & 7) * 8;       // column-8-group
    const int rt = t >> 3;            // 0..31
    const int gid = blockIdx.x;
    const int blk0 = (c8 >> 3) ^ ((rt >> 3) & 7);          // LDS store swizzle, row=rt
    const int blk1 = (c8 >> 3) ^ (((rt + 32) >> 3) & 7);   // row=rt+32

    if (gid < 1024) {
        // ---- x path: tiles 4*gid .. 4*gid+3 ----
        const int base15 = (gid & 3) * 4;              // (id0&15)/... d0_tau = (base15+tau)*64
        const int n0 = ((gid >> 2) & 63) * 64;
        const int b = gid >> 8;
        const float* xr  = x + (size_t)b * 4194304 + (size_t)(n0 + rt) * 1024 + c8;
        const float* xr2 = xr + 32 * 1024;
        uint16_t* xbr  = xb + (size_t)(b * 4096 + n0 + rt) * 1024 + c8;
        uint16_t* xbr2 = xbr + 32 * 1024;
        uint16_t* oT = xT + (size_t)b * 4194304 + c8;  // + (d)*4096 later (n0 folded)

        float4 c0a, c0b, c1a, c1b;
        {
            int d = base15 * 64;
            c0a = *(const float4*)(xr + d);  c0b = *(const float4*)(xr + d + 4);
            c1a = *(const float4*)(xr2 + d); c1b = *(const float4*)(xr2 + d + 4);
        }
#pragma unroll
        for (int tau = 0; tau < 4; tau++) {
            const int dt = (base15 + tau) * 64;
            float4 na0 = c0a, nb0 = c0b, na1 = c1a, nb1 = c1b;
            if (tau < 3) {
                int dn = dt + 64;
                na0 = *(const float4*)(xr + dn);  nb0 = *(const float4*)(xr + dn + 4);
                na1 = *(const float4*)(xr2 + dn); nb1 = *(const float4*)(xr2 + dn + 4);
            }
            uint4 p0 = pack8(c0a, c0b);
            uint4 p1 = pack8(c1a, c1b);
            *(uint4*)&xbr[dt]  = p0;
            *(uint4*)&xbr2[dt] = p1;
            *(uint4*)&tile[rt * 64 + blk0 * 8] = p0;
            *(uint4*)&tile[(rt + 32) * 64 + blk1 * 8] = p1;
            __syncthreads();
#pragma unroll
            for (int p = 0; p < 2; p++) {
                int a = p * 32 + rt;
                uint16_t vv[8];
#pragma unroll
                for (int k = 0; k < 8; k++) {
                    int tok = c8 + k;
                    int bk = (a >> 3) ^ ((tok >> 3) & 7);
                    vv[k] = tile[tok * 64 + bk * 8 + (a & 7)];
                }
                uint4 pk;
                pk.x = (uint32_t)vv[0] | ((uint32_t)vv[1] << 16);
                pk.y = (uint32_t)vv[2] | ((uint32_t)vv[3] << 16);
                pk.z = (uint32_t)vv[4] | ((uint32_t)vv[5] << 16);
                pk.w = (uint32_t)vv[6] | ((uint32_t)vv[7] << 16);
                *(uint4*)&oT[(size_t)(dt + a) * 4096 + n0] = pk;
            }
            __syncthreads();
            c0a = na0; c0b = nb0; c1a = na1; c1b = nb1;
        }
    } else {
        // ---- weight path: tiles 4*(gid-1024) .. +3 ----
        const int gw = gid - 1024;
        const int base15 = (gw & 3) * 4;               // c0_tau = (base15+tau)*64
        const int r0 = ((gw >> 2) & 15) * 64;
        const int m = gw >> 6;
        const float* in = wp.p[m];
        const float* wr  = in + (size_t)(r0 + rt) * 1024 + c8;
        const float* wr2 = wr + 32 * 1024;
        uint16_t* o = Wt + (size_t)m * 1048576 + r0 + c8;   // + e*1024 later

        float4 c0a, c0b, c1a, c1b;
        {
            int d = base15 * 64;
            c0a = *(const float4*)(wr + d);  c0b = *(const float4*)(wr + d + 4);
            c1a = *(const float4*)(wr2 + d); c1b = *(const float4*)(wr2 + d + 4);
        }
#pragma unroll
        for (int tau = 0; tau < 4; tau++) {
            const int ct = (base15 + tau) * 64;
            float4 na0 = c0a, nb0 = c0b, na1 = c1a, nb1 = c1b;
            if (tau < 3) {
                int cn = ct + 64;
                na0 = *(const float4*)(wr + cn);  nb0 = *(const float4*)(wr + cn + 4);
                na1 = *(const float4*)(wr2 + cn); nb1 = *(const float4*)(wr2 + cn + 4);
            }
            uint4 p0 = pack8(c0a, c0b);
            uint4 p1 = pack8(c1a, c1b);
            *(uint4*)&tile[rt * 64 + blk0 * 8] = p0;
            *(uint4*)&tile[(rt + 32) * 64 + blk1 * 8] = p1;
            __syncthreads();
#pragma unroll
            for (int p = 0; p < 2; p++) {
                int a = p * 32 + rt;              // e-local
                uint16_t vv[8];
#pragma unroll
                for (int k = 0; k < 8; k++) {
                    int dd = c8 + k;              // d-local
                    int bk = (a >> 3) ^ ((dd >> 3) & 7);
                    vv[k] = tile[dd * 64 + bk * 8 + (a & 7)];
                }
                uint4 pk;
                pk.x = (uint32_t)vv[0] | ((uint32_t)vv[1] << 16);
                pk.y = (uint32_t)vv[2] | ((uint32_t)vv[3] << 16);
                pk.z = (uint32_t)vv[4] | ((uint32_t)vv[5] << 16);
                pk.w = (uint32_t)vv[6] | ((uint32_t)vv[7] << 16);
                *(uint4*)&o[(size_t)(ct + a) * 1024] = pk;
            }
            __syncthreads();
            c0a = na0; c0b = nb0; c1a = na1; c1b = nb1;
        }
    }
}

// ---------- qbuf dual-B gated projection (verified; single launch) ----------
__global__ __launch_bounds__(512, 2) void proj_gate8(const uint16_t* __restrict__ A,
                                                     const uint16_t* __restrict__ Wt,
                                                     uint16_t* __restrict__ Q) {
    __shared__ uint16_t lds[65536];   // 128 KB = 4 qbufs x 16384 u16
    const int t = threadIdx.x;
    const int wave = t >> 6;
    const int lane = t & 63;
    int bx, by, bz;
    swz3(bx, by, bz);
    const int m0 = by * 256;
    const int e0 = bx * 128;
    const uint16_t* B1 = Wt + (size_t)e0 * 1024;
    const uint16_t* B2 = Wt + 1048576 + (size_t)e0 * 1024;
    const int wm = (wave >> 1) * 64;
    const int wn = (wave & 1) * 64;

    int LsA0 = t * 16;
    int LsA1 = 8192 + t * 16;
    int gbA0 = LsA0 ^ (((LsA0 >> 7) & 7) << 4);
    int gbA1 = LsA1 ^ (((LsA1 >> 7) & 7) << 4);
    int gbB  = gbA0;
    const uint16_t* srcA0 = A + (size_t)(m0 + (gbA0 >> 6)) * 1024 + ((gbA0 & 63) >> 1);
    const uint16_t* srcA1 = A + (size_t)(m0 + (gbA1 >> 6)) * 1024 + ((gbA1 & 63) >> 1);
    const uint16_t* srcB1 = B1 + (size_t)(gbB >> 6) * 1024 + ((gbB & 63) >> 1);
    const uint16_t* srcB2 = B2 + (size_t)(gbB >> 6) * 1024 + ((gbB & 63) >> 1);

    auto STAGE = [&](int kt_, int ks_) {
        const int h = (2 * kt_ + ks_) & 3;
        const int kb = kt_ * 64 + ks_ * 32;
        uint16_t* db = lds + h * 16384 + (wave << 9);
        gll16(srcA0 + kb, db);
        gll16(srcA1 + kb, db + 4096);
        gll16(srcB1 + kb, db + 8192);
        gll16(srcB2 + kb, db + 12288);
    };

    const int cb = (lane >> 4) << 4;
    int aoff[4], b1off[4], b2off[4];
#pragma unroll
    for (int i = 0; i < 4; i++) {
        int g = (wm + i * 16 + (lane & 15)) * 64 + cb;
        aoff[i] = (g ^ (((g >> 7) & 7) << 4)) >> 1;
    }
#pragma unroll
    for (int j = 0; j < 4; j++) {
        int g = (wn + j * 16 + (lane & 15)) * 64 + cb;
        int sw = (g ^ (((g >> 7) & 7) << 4)) >> 1;
        b1off[j] = 8192 + sw;
        b2off[j] = 12288 + sw;
    }

    f32x4 acc1[4][4] = {};
    f32x4 acc2[4][4] = {};

    STAGE(0, 0); STAGE(0, 1); STAGE(1, 0); STAGE(1, 1);
    asm volatile("s_waitcnt vmcnt(12)" ::: "memory");
    __builtin_amdgcn_s_barrier();

    for (int kt = 0; kt < 16; ++kt) {
        const uint16_t* lb0 = lds + ((2 * kt) & 3) * 16384;
        const uint16_t* lb1 = lds + ((2 * kt + 1) & 3) * 16384;
        bf16x8 af[4], bq[4];

        // phase 1: A(ks0)+B1(ks0) -> acc1
#pragma unroll
        for (int i = 0; i < 4; i++) af[i] = *(const bf16x8*)&lb0[aoff[i]];
#pragma unroll
        for (int j = 0; j < 4; j++) bq[j] = *(const bf16x8*)&lb0[b1off[j]];
        __builtin_amdgcn_s_barrier();
        asm volatile("s_waitcnt lgkmcnt(0)" ::: "memory");
        __builtin_amdgcn_sched_barrier(0);
        __builtin_amdgcn_s_setprio(1);
#pragma unroll
        for (int i = 0; i < 4; i++)
#pragma unroll
            for (int j = 0; j < 4; j++)
                acc1[i][j] = __builtin_amdgcn_mfma_f32_16x16x32_bf16(af[i], bq[j],
                                                                     acc1[i][j], 0, 0, 0);
        __builtin_amdgcn_s_setprio(0);
        __builtin_amdgcn_s_barrier();

        // phase 2: B2(ks0) -> acc2
#pragma unroll
        for (int j = 0; j < 4; j++) bq[j] = *(const bf16x8*)&lb0[b2off[j]];
        __builtin_amdgcn_s_barrier();
        asm volatile("s_waitcnt lgkmcnt(0)" ::: "memory");
        __builtin_amdgcn_sched_barrier(0);
        __builtin_amdgcn_s_setprio(1);
#pragma unroll
        for (int i = 0; i < 4; i++)
#pragma unroll
            for (int j = 0; j < 4; j++)
                acc2[i][j] = __builtin_amdgcn_mfma_f32_16x16x32_bf16(af[i], bq[j],
                                                                     acc2[i][j], 0, 0, 0);
        __builtin_amdgcn_s_setprio(0);
        if (kt < 15) { asm volatile("s_waitcnt vmcnt(8)" ::: "memory"); }
        else         { asm volatile("s_waitcnt vmcnt(0)" ::: "memory"); }
        __builtin_amdgcn_s_barrier();
        if (kt < 14) STAGE(kt + 2, 0);

        // phase 3: A(ks1)+B1(ks1) -> acc1
#pragma unroll
        for (int i = 0; i < 4; i++) af[i] = *(const bf16x8*)&lb1[aoff[i]];
#pragma unroll
        for (int j = 0; j < 4; j++) bq[j] = *(const bf16x8*)&lb1[b1off[j]];
        __builtin_amdgcn_s_barrier();
        asm volatile("s_waitcnt lgkmcnt(0)" ::: "memory");
        __builtin_amdgcn_sched_barrier(0);
        __builtin_amdgcn_s_setprio(1);
#pragma unroll
        for (int i = 0; i < 4; i++)
#pragma unroll
            for (int j = 0; j < 4; j++)
                acc1[i][j] = __builtin_amdgcn_mfma_f32_16x16x32_bf16(af[i], bq[j],
                                                                     acc1[i][j], 0, 0, 0);
        __builtin_amdgcn_s_setprio(0);
        __builtin_amdgcn_s_barrier();

        // phase 4: B2(ks1) -> acc2
#pragma unroll
        for (int j = 0; j < 4; j++) bq[j] = *(const bf16x8*)&lb1[b2off[j]];
        __builtin_amdgcn_s_barrier();
        asm volatile("s_waitcnt lgkmcnt(0)" ::: "memory");
        __builtin_amdgcn_sched_barrier(0);
        __builtin_amdgcn_s_setprio(1);
#pragma unroll
        for (int i = 0; i < 4; i++)
#pragma unroll
            for (int j = 0; j < 4; j++)
                acc2[i][j] = __builtin_amdgcn_mfma_f32_16x16x32_bf16(af[i], bq[j],
                                                                     acc2[i][j], 0, 0, 0);
        __builtin_amdgcn_s_setprio(0);
        if (kt < 14)       { asm volatile("s_waitcnt vmcnt(8)" ::: "memory"); }
        else if (kt == 14) { asm volatile("s_waitcnt vmcnt(4)" ::: "memory"); }
        else               { asm volatile("s_waitcnt vmcnt(0)" ::: "memory"); }
        __builtin_amdgcn_s_barrier();
        if (kt < 14) STAGE(kt + 2, 1);
    }

    const int rl = (lane >> 4) * 4;
    const int cl = lane & 15;
#pragma unroll
    for (int i = 0; i < 4; i++)
#pragma unroll
        for (int j = 0; j < 4; j++)
#pragma unroll
            for (int r = 0; r < 4; r++) {
                float g = acc1[i][j][r] * acc2[i][j][r];
                Q[(size_t)(m0 + wm + i * 16 + rl + r) * 1024 + e0 + wn + j * 16 + cl] = f2b(g);
            }
}

// ---------- qbuf Gram GEMM: P[z=(batch,ks)] = xT-slice @ xT-slice^T ----------
__global__ __launch_bounds__(512, 2) void gram8(const uint16_t* __restrict__ xT,
                                                float* __restrict__ P) {
    __shared__ uint16_t lds[49152];   // 96 KB = 4 qbufs x 12288 u16
    const int t = threadIdx.x;
    const int wave = t >> 6;
    const int lane = t & 63;
    int bx, by, bz;
    swz3(bx, by, bz);
    const int m0 = by * 256;
    const int n0 = bx * 128;
    const int batch = bz >> 1, ks = bz & 1;
    const uint16_t* Xb = xT + (size_t)batch * 4194304 + ks * 2048;
    const int wm = (wave >> 1) * 64;
    const int wn = (wave & 1) * 64;

    int LsA0 = t * 16;
    int LsA1 = 8192 + t * 16;
    int gbA0 = LsA0 ^ (((LsA0 >> 7) & 7) << 4);
    int gbA1 = LsA1 ^ (((LsA1 >> 7) & 7) << 4);
    int gbB  = gbA0;
    const uint16_t* srcA0 = Xb + (size_t)(m0 + (gbA0 >> 6)) * 4096 + ((gbA0 & 63) >> 1);
    const uint16_t* srcA1 = Xb + (size_t)(m0 + (gbA1 >> 6)) * 4096 + ((gbA1 & 63) >> 1);
    const uint16_t* srcB  = Xb + (size_t)(n0 + (gbB  >> 6)) * 4096 + ((gbB  & 63) >> 1);

    auto STAGE = [&](int kt_, int ks2_) {
        const int h = (2 * kt_ + ks2_) & 3;
        const int kb = kt_ * 64 + ks2_ * 32;
        uint16_t* db = lds + h * 12288 + (wave << 9);
        gll16(srcA0 + kb, db);            // A rows   0..127
        gll16(srcA1 + kb, db + 4096);     // A rows 128..255
        gll16(srcB  + kb, db + 8192);     // B rows   0..127
    };

    const int cb = (lane >> 4) << 4;
    int aoff[4], boff[4];
#pragma unroll
    for (int i = 0; i < 4; i++) {
        int g = (wm + i * 16 + (lane & 15)) * 64 + cb;
        aoff[i] = (g ^ (((g >> 7) & 7) << 4)) >> 1;
    }
#pragma unroll
    for (int j = 0; j < 4; j++) {
        int g = (wn + j * 16 + (lane & 15)) * 64 + cb;
        boff[j] = 8192 + ((g ^ (((g >> 7) & 7) << 4)) >> 1);
    }

    f32x4 acc[4][4] = {};

    STAGE(0, 0); STAGE(0, 1); STAGE(1, 0); STAGE(1, 1);
    asm volatile("s_waitcnt vmcnt(9)" ::: "memory");
    __builtin_amdgcn_s_barrier();

    for (int kt = 0; kt < 32; ++kt) {
        const uint16_t* lb0 = lds + ((2 * kt) & 3) * 12288;
        const uint16_t* lb1 = lds + ((2 * kt + 1) & 3) * 12288;
        bf16x8 af[4], bq[4];

        // phase ks2=0
#pragma unroll
        for (int i = 0; i < 4; i++) af[i] = *(const bf16x8*)&lb0[aoff[i]];
#pragma unroll
        for (int j = 0; j < 4; j++) bq[j] = *(const bf16x8*)&lb0[boff[j]];
        __builtin_amdgcn_s_barrier();
        asm volatile("s_waitcnt lgkmcnt(0)" ::: "memory");
        __builtin_amdgcn_sched_barrier(0);
        __builtin_amdgcn_s_setprio(1);
#pragma unroll
        for (int i = 0; i < 4; i++)
#pragma unroll
            for (int j = 0; j < 4; j++)
                acc[i][j] = __builtin_amdgcn_mfma_f32_16x16x32_bf16(af[i], bq[j],
                                                                    acc[i][j], 0, 0, 0);
        __builtin_amdgcn_s_setprio(0);
        if (kt < 31) { asm volatile("s_waitcnt vmcnt(6)" ::: "memory"); }
        else         { asm volatile("s_waitcnt vmcnt(0)" ::: "memory"); }
        __builtin_amdgcn_s_barrier();
        if (kt < 30) STAGE(kt + 2, 0);

        // phase ks2=1
#pragma unroll
        for (int i = 0; i < 4; i++) af[i] = *(const bf16x8*)&lb1[aoff[i]];
#pragma unroll
        for (int j = 0; j < 4; j++) bq[j] = *(const bf16x8*)&lb1[boff[j]];
        __builtin_amdgcn_s_barrier();
        asm volatile("s_waitcnt lgkmcnt(0)" ::: "memory");
        __builtin_amdgcn_sched_barrier(0);
        __builtin_amdgcn_s_setprio(1);
#pragma unroll
        for (int i = 0; i < 4; i++)
#pragma unroll
            for (int j = 0; j < 4; j++)
                acc[i][j] = __builtin_amdgcn_mfma_f32_16x16x32_bf16(af[i], bq[j],
                                                                    acc[i][j], 0, 0, 0);
        __builtin_amdgcn_s_setprio(0);
        if (kt < 30)       { asm volatile("s_waitcnt vmcnt(6)" ::: "memory"); }
        else if (kt == 30) { asm volatile("s_waitcnt vmcnt(3)" ::: "memory"); }
        else               { asm volatile("s_waitcnt vmcnt(0)" ::: "memory"); }
        __builtin_amdgcn_s_barrier();
        if (kt < 30) STAGE(kt + 2, 1);
    }

    float* Pb = P + (size_t)bz * 1048576;
    const int crow = m0 + wm + (lane >> 4) * 4;
    const int ccol = n0 + wn + (lane & 15);
#pragma unroll
    for (int i = 0; i < 4; i++)
#pragma unroll
        for (int j = 0; j < 4; j++)
#pragma unroll
            for (int r = 0; r < 4; r++)
                Pb[(size_t)(crow + i * 16 + r) * 1024 + ccol + j * 16] = acc[i][j][r];
}

// ---------- reduce 2 fp32 partials -> bf16 (G = x^T x per batch) ----------
__global__ __launch_bounds__(256) void reduce_kv(const float4* __restrict__ P,
                                                 uint2* __restrict__ G) {
    int i = blockIdx.x * 256 + threadIdx.x;
    int b = i >> 18;
    int r = i & 262143;
    const float4* base = P + (size_t)b * 524288 + r;
    float4 s0 = base[0];
    float4 s1 = base[262144];
    float x = s0.x + s1.x;
    float y = s0.y + s1.y;
    float zz = s0.z + s1.z;
    float w = s0.w + s1.w;
    uint2 o;
    o.x = (uint32_t)f2b(x) | ((uint32_t)f2b(y) << 16);
    o.y = (uint32_t)f2b(zz) | ((uint32_t)f2b(w) << 16);
    G[i] = o;
}

// ---------- generic 128x128-tile GEMM, K=1024, bf16 out ----------
__global__ __launch_bounds__(256) void gemm_nt_bf16(const uint16_t* __restrict__ A,
                                                    int lda, int az,
                                                    const uint16_t* __restrict__ Bt,
                                                    int ldb,
                                                    uint16_t* __restrict__ C,
                                                    int ldc, int cz) {
    int bxs, bys, bzs;
    swz3(bxs, bys, bzs);
    const uint16_t* Ab = A + (size_t)bzs * az;
    uint16_t* Cb = C + (size_t)bzs * cz;

    __shared__ uint16_t lA[4096];
    __shared__ uint16_t lB[4096];

    const int t = threadIdx.x;
    const int wave = t >> 6;
    const int lane = t & 63;
    const int m0 = bys * 128;
    const int n0 = bxs * 128;
    const int wm = (wave >> 1) * 64;
    const int wn = (wave & 1) * 64;

    const uint16_t* gA0 = Ab + (size_t)(m0 + (t >> 2)) * lda + (t & 3) * 8;
    const uint16_t* gB0 = Bt + (size_t)(n0 + (t >> 2)) * ldb + (t & 3) * 8;
    uint16_t* lA0 = lA + wave * 512;
    uint16_t* lA1 = lA + 2048 + wave * 512;
    uint16_t* lB0 = lB + wave * 512;
    uint16_t* lB1 = lB + 2048 + wave * 512;

    f32x4 acc[4][4] = {};

    const int arow = wm + (lane & 15);
    const int brow = wn + (lane & 15);
    const int koff = (lane >> 4) * 8;

    for (int k0 = 0; k0 < 1024; k0 += 32) {
        __syncthreads();
        gll16(gA0 + k0, lA0);
        gll16(gA0 + (size_t)64 * lda + k0, lA1);
        gll16(gB0 + k0, lB0);
        gll16(gB0 + (size_t)64 * ldb + k0, lB1);
        __syncthreads();

        bf16x8 af[4], bfr[4];
#pragma unroll
        for (int i = 0; i < 4; i++)
            af[i] = *(const bf16x8*)&lA[(arow + i * 16) * 32 + koff];
#pragma unroll
        for (int i = 0; i < 4; i++)
            bfr[i] = *(const bf16x8*)&lB[(brow + i * 16) * 32 + koff];
#pragma unroll
        for (int i = 0; i < 4; i++)
#pragma unroll
            for (int j = 0; j < 4; j++)
                acc[i][j] = __builtin_amdgcn_mfma_f32_16x16x32_bf16(af[i], bfr[j],
                                                                    acc[i][j], 0, 0, 0);
    }

    const int crow = m0 + wm + (lane >> 4) * 4;
    const int ccol = n0 + wn + (lane & 15);
#pragma unroll
    for (int i = 0; i < 4; i++)
#pragma unroll
        for (int j = 0; j < 4; j++)
#pragma unroll
            for (int r = 0; r < 4; r++)
                Cb[(size_t)(crow + i * 16 + r) * ldc + ccol + j * 16] = f2b(acc[i][j][r]);
}

// ---------- qbuf out GEMM: out = Q @ kvT^T, fp32 (verified) ----------
__global__ __launch_bounds__(512, 2) void gemm_out8(const uint16_t* __restrict__ A,
                                                    const uint16_t* __restrict__ kvT,
                                                    float* __restrict__ C) {
    __shared__ uint16_t lds[65536];
    const int t = threadIdx.x;
    const int wave = t >> 6;
    const int lane = t & 63;
    int bx, by, bz;
    swz3(bx, by, bz);
    const int m0 = by * 256;
    const int n0 = bx * 256;
    const int batch = by >> 4;
    const uint16_t* Bb = kvT + (size_t)batch * 1048576 + (size_t)n0 * 1024;
    const int wm = (wave >> 2) * 128;
    const int wn = (wave & 3) * 64;

    int Ls0 = t * 16;
    int Ls1 = 8192 + t * 16;
    int gb0 = Ls0 ^ (((Ls0 >> 7) & 7) << 4);
    int gb1 = Ls1 ^ (((Ls1 >> 7) & 7) << 4);
    const uint16_t* srcA0 = A + (size_t)(m0 + (gb0 >> 6)) * 1024 + ((gb0 & 63) >> 1);
    const uint16_t* srcA1 = A + (size_t)(m0 + (gb1 >> 6)) * 1024 + ((gb1 & 63) >> 1);
    const uint16_t* srcB0 = Bb + (size_t)(gb0 >> 6) * 1024 + ((gb0 & 63) >> 1);
    const uint16_t* srcB1 = Bb + (size_t)(gb1 >> 6) * 1024 + ((gb1 & 63) >> 1);

    auto STAGE = [&](int kt_, int ks_) {
        const int h = (2 * kt_ + ks_) & 3;
        const int kb = kt_ * 64 + ks_ * 32;
        uint16_t* db = lds + h * 16384 + (wave << 9);
        gll16(srcA0 + kb, db);
        gll16(srcA1 + kb, db + 4096);
        gll16(srcB0 + kb, db + 8192);
        gll16(srcB1 + kb, db + 12288);
    };

    const int cb = (lane >> 4) << 4;
    int aoff[8], boff[4];
#pragma unroll
    for (int i = 0; i < 8; i++) {
        int g = (wm + i * 16 + (lane & 15)) * 64 + cb;
        aoff[i] = (g ^ (((g >> 7) & 7) << 4)) >> 1;
    }
#pragma unroll
    for (int j = 0; j < 4; j++) {
        int g = (wn + j * 16 + (lane & 15)) * 64 + cb;
        boff[j] = 8192 + ((g ^ (((g >> 7) & 7) << 4)) >> 1);
    }

    f32x4 acc[8][4] = {};

    STAGE(0, 0); STAGE(0, 1); STAGE(1, 0); STAGE(1, 1);
    asm volatile("s_waitcnt vmcnt(12)" ::: "memory");
    __builtin_amdgcn_s_barrier();

    for (int kt = 0; kt < 16; ++kt) {
        const uint16_t* lb0 = lds + ((2 * kt) & 3) * 16384;
        const uint16_t* lb1 = lds + ((2 * kt + 1) & 3) * 16384;
        bf16x8 af[8], bq[4];

        // phase ks0
#pragma unroll
        for (int i = 0; i < 8; i++) af[i] = *(const bf16x8*)&lb0[aoff[i]];
#pragma unroll
        for (int j = 0; j < 4; j++) bq[j] = *(const bf16x8*)&lb0[boff[j]];
        __builtin_amdgcn_s_barrier();
        asm volatile("s_waitcnt lgkmcnt(0)" ::: "memory");
        __builtin_amdgcn_sched_barrier(0);
        __builtin_amdgcn_s_setprio(1);
#pragma unroll
        for (int i = 0; i < 8; i++)
#pragma unroll
            for (int j = 0; j < 4; j++)
                acc[i][j] = __builtin_amdgcn_mfma_f32_16x16x32_bf16(af[i], bq[j],
                                                                    acc[i][j], 0, 0, 0);
        __builtin_amdgcn_s_setprio(0);
        if (kt < 15) { asm volatile("s_waitcnt vmcnt(8)" ::: "memory"); }
        else         { asm volatile("s_waitcnt vmcnt(0)" ::: "memory"); }
        __builtin_amdgcn_s_barrier();
        if (kt < 14) STAGE(kt + 2, 0);

        // phase ks1
#pragma unroll
        for (int i = 0; i < 8; i++) af[i] = *(const bf16x8*)&lb1[aoff[i]];
#pragma unroll
        for (int j = 0; j < 4; j++) bq[j] = *(const bf16x8*)&lb1[boff[j]];
        __builtin_amdgcn_s_barrier();
        asm volatile("s_waitcnt lgkmcnt(0)" ::: "memory");
        __builtin_amdgcn_sched_barrier(0);
        __builtin_amdgcn_s_setprio(1);
#pragma unroll
        for (int i = 0; i < 8; i++)
#pragma unroll
            for (int j = 0; j < 4; j++)
                acc[i][j] = __builtin_amdgcn_mfma_f32_16x16x32_bf16(af[i], bq[j],
                                                                    acc[i][j], 0, 0, 0);
        __builtin_amdgcn_s_setprio(0);
        if (kt < 14)       { asm volatile("s_waitcnt vmcnt(8)" ::: "memory"); }
        else if (kt == 14) { asm volatile("s_waitcnt vmcnt(4)" ::: "memory"); }
        else               { asm volatile("s_waitcnt vmcnt(0)" ::: "memory"); }
        __builtin_amdgcn_s_barrier();
        if (kt < 14) STAGE(kt + 2, 1);
    }

    const int rl = (lane >> 4) * 4;
    const int cl = lane & 15;
#pragma unroll
    for (int i = 0; i < 8; i++)
#pragma unroll
        for (int j = 0; j < 4; j++)
#pragma unroll
            for (int r = 0; r < 4; r++)
                C[(size_t)(m0 + wm + i * 16 + rl + r) * 1024 + n0 + wn + j * 16 + cl] =
                    acc[i][j][r];
}

// ---------- launch ----------
extern "C" void kernel_launch(void* const* d_in, const int* in_sizes, int n_in,
                              void* d_out, int out_size, void* d_ws, size_t ws_size,
                              hipStream_t stream) {
    const float* x = (const float*)d_in[0];

    uint16_t* ws  = (uint16_t*)d_ws;
    uint16_t* xb  = ws;                        // [0,32MB)    x bf16 row-major
    uint16_t* xT  = ws + 16777216;             // [32,64MB)   x^T bf16 [4][1024][4096]
    uint16_t* Wt  = ws + 33554432;             // [64,72MB)   W^T x4 bf16
    uint16_t* Q   = ws + 37748736;             // [72,104MB)  gated query bf16
    float*    P   = (float*)(ws + 54525952);   // [104,136MB) fp32 Gram partials
    uint16_t* G   = ws + 71303168;             // [136,144MB) G = x^T x bf16
    uint16_t* H   = ws + 75497472;             // [144,152MB) H = Wv^T G  [1024][4096]
    uint16_t* kvT = ws + 79691776;             // [152,160MB) kv^T bf16 [4][1024][1024]

    // 1. fused prep: 4 tiles/block, pipelined (latency-hiding)
    Ptr4 wp;
    wp.p[0] = (const float*)d_in[1];
    wp.p[1] = (const float*)d_in[2];
    wp.p[2] = (const float*)d_in[3];
    wp.p[3] = (const float*)d_in[4];
    prep<<<1280, 256, 0, stream>>>(x, xb, xT, wp, Wt);

    // 2. gated query projection (single launch, qbuf pipeline + XCD swizzle)
    proj_gate8<<<dim3(8, 64), 512, 0, stream>>>(xb, Wt, Q);

    // 3. Gram partials: qbuf pipeline, split-K=2, 256x128 tiles (256 blocks)
    gram8<<<dim3(8, 4, 8), 512, 0, stream>>>(xT, P);

    // 4. reduce partials -> G bf16
    reduce_kv<<<4096, 256, 0, stream>>>((const float4*)P, (uint2*)G);

    // 5. H = Wv^T @ G  (G symmetric -> rows as B)
    gemm_nt_bf16<<<dim3(32, 8, 1), 256, 0, stream>>>(Wt + 3 * 1048576, 1024, 0,
                                                     G, 1024, H, 4096, 0);

    // 6. kvT[b] = H[:, b*1024:(b+1)*1024] @ Wk
    gemm_nt_bf16<<<dim3(8, 8, 4), 256, 0, stream>>>(H, 4096, 1024,
                                                    Wt + 2 * 1048576, 1024,
                                                    kvT, 1024, 1048576);

    // 7. out = Q @ kvT^T (qbuf pipeline)
    gemm_out8<<<dim3(4, 64), 512, 0, stream>>>(Q, kvT, (float*)d_out);
}